// Round 2
// 3516.229 us; speedup vs baseline: 2.9707x; 2.9707x over previous
//
#include <hip/hip_runtime.h>
#include <math.h>

// Problem constants
#define Lc 4
#define Hc 4
#define Bc 2
#define Tc 1024
#define Dc 1024
#define DFFc 4096
#define Vc 32000
#define BTc (Bc * Tc)
#define HDc (Hc * Dc) // 4096

typedef unsigned int u32;
typedef unsigned short u16;
typedef __attribute__((ext_vector_type(8))) short bh8;   // 8 x bf16 (4 VGPR)
typedef __attribute__((ext_vector_type(4))) float f4v;   // MFMA accumulator

constexpr float EPSc = 1e-5f;
constexpr float SCALEc = 0.03125f; // 1/sqrt(1024)

// ---------------- conversion helpers ----------------
__device__ __forceinline__ u16 f2bf(float f) {
    u32 u = __builtin_bit_cast(u32, f);
    u = u + 0x7FFFu + ((u >> 16) & 1u); // RNE
    return (u16)(u >> 16);
}
__device__ __forceinline__ u32 cvt2(float a, float b) {
    return (u32)f2bf(a) | ((u32)f2bf(b) << 16); // lo = a, hi = b
}
typedef const __attribute__((address_space(1))) void* gas1_t;
typedef __attribute__((address_space(3))) void* las3_t;
__device__ __forceinline__ void gload16(const void* g, void* l) {
    // async global->LDS, 16B per lane, LDS dest = wave-uniform base + lane*16
    __builtin_amdgcn_global_load_lds((gas1_t)g, (las3_t)l, 16, 0, 0);
}

// ---------------- reduction helpers (blockDim.x == 256) ----------------
__device__ __forceinline__ float block_reduce_max(float v) {
    #pragma unroll
    for (int o = 32; o > 0; o >>= 1) v = fmaxf(v, __shfl_down(v, o, 64));
    __shared__ float sm_[4];
    __syncthreads();
    if ((threadIdx.x & 63) == 0) sm_[threadIdx.x >> 6] = v;
    __syncthreads();
    return fmaxf(fmaxf(sm_[0], sm_[1]), fmaxf(sm_[2], sm_[3]));
}

__device__ __forceinline__ float block_reduce_sum(float v) {
    #pragma unroll
    for (int o = 32; o > 0; o >>= 1) v += __shfl_down(v, o, 64);
    __shared__ float ss_[4];
    __syncthreads();
    if ((threadIdx.x & 63) == 0) ss_[threadIdx.x >> 6] = v;
    __syncthreads();
    return ss_[0] + ss_[1] + ss_[2] + ss_[3];
}

// ---------------- embed: h = token_emb[x] + pos_embed (fp32) ----------------
__global__ __launch_bounds__(256) void embed_kernel(const int* __restrict__ x,
                                                    const float* __restrict__ emb,
                                                    float* __restrict__ h) {
    long idx = (long)blockIdx.x * 256 + threadIdx.x; // < BT*D
    int d = (int)(idx & (Dc - 1));
    long bt = idx >> 10;
    int t = (int)(bt & (Tc - 1));
    int tok = x[bt];
    float denom = powf(10000.0f, (float)(2 * (d >> 1)) * (1.0f / Dc));
    float ang = (float)t / denom;
    float p = (d & 1) ? cosf(ang) : sinf(ang);
    h[idx] = emb[(long)tok * Dc + d] + p;
}

// ---------------- layernorm over D=1024 -> bf16 output ----------------
__global__ __launch_bounds__(256) void layernorm_kernel(const float* __restrict__ X,
                                                        const float* __restrict__ g,
                                                        const float* __restrict__ b,
                                                        u16* __restrict__ Y) {
    long row = blockIdx.x;
    float4 v = ((const float4*)(X + row * Dc))[threadIdx.x];
    float s  = v.x + v.y + v.z + v.w;
    float sq = v.x * v.x + v.y * v.y + v.z * v.z + v.w * v.w;
    #pragma unroll
    for (int o = 32; o > 0; o >>= 1) {
        s  += __shfl_down(s, o, 64);
        sq += __shfl_down(sq, o, 64);
    }
    __shared__ float ssum[4], ssq[4];
    if ((threadIdx.x & 63) == 0) { ssum[threadIdx.x >> 6] = s; ssq[threadIdx.x >> 6] = sq; }
    __syncthreads();
    s  = ssum[0] + ssum[1] + ssum[2] + ssum[3];
    sq = ssq[0] + ssq[1] + ssq[2] + ssq[3];
    float mu  = s * (1.0f / Dc);
    float var = sq * (1.0f / Dc) - mu * mu;
    float inv = rsqrtf(var + EPSc);
    float4 gv = ((const float4*)g)[threadIdx.x];
    float4 bv = ((const float4*)b)[threadIdx.x];
    float o0 = (v.x - mu) * inv * gv.x + bv.x;
    float o1 = (v.y - mu) * inv * gv.y + bv.y;
    float o2 = (v.z - mu) * inv * gv.z + bv.z;
    float o3 = (v.w - mu) * inv * gv.w + bv.w;
    uint2 o; o.x = cvt2(o0, o1); o.y = cvt2(o2, o3);
    ((uint2*)(Y + row * Dc))[threadIdx.x] = o;
}

// ---------------- causal softmax: fp32 S in, bf16 P out (applies scale) ----------------
__global__ __launch_bounds__(256) void softmax_causal_kernel(const float* __restrict__ S,
                                                             u16* __restrict__ P) {
    int t = blockIdx.x;
    long z = blockIdx.y;
    const float* row = S + (z * Tc + t) * (long)Tc;
    u16* prow = P + (z * Tc + t) * (long)Tc;
    int n = t + 1;
    float m = -INFINITY;
    for (int s = threadIdx.x; s < n; s += 256) m = fmaxf(m, row[s] * SCALEc);
    m = block_reduce_max(m);
    float sum = 0.0f;
    for (int s = threadIdx.x; s < n; s += 256) sum += expf(row[s] * SCALEc - m);
    sum = block_reduce_sum(sum);
    float r = 1.0f / sum;
    for (int s = threadIdx.x; s < Tc; s += 256) {
        float p = (s < n) ? expf(row[s] * SCALEc - m) * r : 0.0f;
        prow[s] = f2bf(p);
    }
}

// ---------------- in-place log_softmax over V=32000, online 2-pass, float4 ----------------
__global__ __launch_bounds__(256) void log_softmax_kernel(float* __restrict__ O) {
    float4* x = (float4*)(O + (long)blockIdx.x * Vc);
    float m = -INFINITY, s = 0.0f;
    for (int i = threadIdx.x; i < Vc / 4; i += 256) {
        float4 v = x[i];
        float mv = fmaxf(fmaxf(v.x, v.y), fmaxf(v.z, v.w));
        if (mv > m) { s *= expf(m - mv); m = mv; }
        s += expf(v.x - m) + expf(v.y - m) + expf(v.z - m) + expf(v.w - m);
    }
    float M = block_reduce_max(m);
    s *= expf(m - M);
    s = block_reduce_sum(s);
    float lse = M + logf(s);
    for (int i = threadIdx.x; i < Vc / 4; i += 256) {
        float4 v = x[i];
        v.x -= lse; v.y -= lse; v.z -= lse; v.w -= lse;
        x[i] = v;
    }
}

// ---------------- bf16 MFMA GEMM, 128x128 tile, BK=32, 4 waves ----------------
// A: bf16 [M][K] row-major (lda), staged via global_load_lds.
// B: TRANSB ? bf16 [N][K] row-major (ldb), staged via global_load_lds
//           : fp32 [K][N] row-major (ldb) weight, scalar-staged + cvt + XOR chunk swizzle.
// Batch z: off = (z/zdiv)*s?o + (z%zdiv)*s?i for A, B, C (element strides).
// HEADB: B += (col0>>10)*sBh (per-head weight slab), bias indexed by global col.
// EPI: 0 fp32 store (+NT option), 1 fp32 residual add, 2 gelu->bf16, 3 (+bias)->bf16,
//      4 (+bias)->bf16 transposed V layout [b][col][t].
// CAUSAL: skip blocks fully above the diagonal. KLIM: Kend = min(K, row0+128).
template <bool TRANSB, bool HEADB, int EPI, bool CAUSAL, bool KLIM, bool NT>
__global__ __launch_bounds__(256) void bgemm(
    const u16* __restrict__ A, const void* __restrict__ Bv,
    const float* __restrict__ bias, void* __restrict__ Cv,
    int M, int N, int K, int lda, int ldb, int ldc,
    int zdiv, long sAo, long sAi, long sBo, long sBi, long sCo, long sCi, long sBh) {
    const int row0 = blockIdx.y * 128;
    const int col0 = blockIdx.x * 128;
    if (CAUSAL && col0 > row0 + 127) return;

    const int z = blockIdx.z;
    const int zo = z / zdiv, zi = z - zo * zdiv;

    __shared__ __align__(16) u16 As[128 * 32];
    __shared__ __align__(16) u16 Bs[128 * 32];

    const int tid = threadIdx.x;
    const int wave = tid >> 6, lane = tid & 63;
    const int wm = wave >> 1, wn = wave & 1;
    const int l15 = lane & 15, lg = lane >> 4;

    // ---- A staging setup (2 x 1KB chunks per wave) ----
    const u16* Ab = A + (long)zo * sAo + (long)zi * sAi;
    const u16* Ag0 = Ab + (long)(row0 + wave * 32 + (lane >> 2)) * lda + (lane & 3) * 8;
    const u16* Ag1 = Ag0 + (long)16 * lda;
    u16* Al0 = As + wave * 1024;
    u16* Al1 = Al0 + 512;

    // ---- B staging setup ----
    const u16* Bg0 = nullptr; const u16* Bg1 = nullptr;
    u16* Bl0 = nullptr; u16* Bl1 = nullptr;
    const float* Bw = nullptr;
    u32* wd0 = nullptr; u32* wd1 = nullptr;
    if (TRANSB) {
        const u16* Bb = (const u16*)Bv + (long)zo * sBo + (long)zi * sBi;
        Bg0 = Bb + (long)(col0 + wave * 32 + (lane >> 2)) * ldb + (lane & 3) * 8;
        Bg1 = Bg0 + (long)16 * ldb;
        Bl0 = Bs + wave * 1024;
        Bl1 = Bl0 + 512;
    } else {
        const float* Bb = (const float*)Bv + (long)zo * sBo + (long)zi * sBi;
        if (HEADB) Bb += (long)(col0 >> 10) * sBh;
        const int nw = tid & 127, kh = tid >> 7;
        const int ncol = (HEADB ? (col0 & 1023) : col0) + nw;
        Bw = Bb + (long)kh * 16 * ldb + ncol;
        const int sw = (nw & 3) ^ ((nw >> 2) & 1); // bank swizzle on 16B chunks
        wd0 = (u32*)(Bs + nw * 32 + (((kh << 1) ^ sw) << 3));
        wd1 = (u32*)(Bs + nw * 32 + ((((kh << 1) | 1) ^ sw) << 3));
    }

    // ---- fragment LDS offsets (fixed across k-loop) ----
    int aoff[4], boff[4];
    #pragma unroll
    for (int m = 0; m < 4; ++m) aoff[m] = (wm * 64 + m * 16 + l15) * 32 + lg * 8;
    #pragma unroll
    for (int n = 0; n < 4; ++n) {
        int r = wn * 64 + n * 16 + l15;
        int g = TRANSB ? lg : (lg ^ ((r & 3) ^ ((r >> 2) & 1)));
        boff[n] = r * 32 + g * 8;
    }

    f4v acc[4][4];
    const f4v fz = {0.f, 0.f, 0.f, 0.f};
    #pragma unroll
    for (int m = 0; m < 4; ++m)
        #pragma unroll
        for (int n = 0; n < 4; ++n) acc[m][n] = fz;

    const int Kend = KLIM ? min(K, row0 + 128) : K;

    for (int k0 = 0; k0 < Kend; k0 += 32) {
        gload16(Ag0, Al0);
        gload16(Ag1, Al1);
        Ag0 += 32; Ag1 += 32;
        if constexpr (TRANSB) {
            gload16(Bg0, Bl0);
            gload16(Bg1, Bl1);
            Bg0 += 32; Bg1 += 32;
        } else {
            float f[16];
            #pragma unroll
            for (int j = 0; j < 16; ++j) f[j] = Bw[(long)j * ldb];
            Bw += (long)32 * ldb;
            uint4 u0, u1;
            u0.x = cvt2(f[0], f[1]);   u0.y = cvt2(f[2], f[3]);
            u0.z = cvt2(f[4], f[5]);   u0.w = cvt2(f[6], f[7]);
            u1.x = cvt2(f[8], f[9]);   u1.y = cvt2(f[10], f[11]);
            u1.z = cvt2(f[12], f[13]); u1.w = cvt2(f[14], f[15]);
            *(uint4*)wd0 = u0;
            *(uint4*)wd1 = u1;
        }
        __syncthreads();
        bh8 af[4], bfr[4];
        #pragma unroll
        for (int m = 0; m < 4; ++m) af[m] = *(const bh8*)(As + aoff[m]);
        #pragma unroll
        for (int n = 0; n < 4; ++n) bfr[n] = *(const bh8*)(Bs + boff[n]);
        #pragma unroll
        for (int m = 0; m < 4; ++m)
            #pragma unroll
            for (int n = 0; n < 4; ++n)
                acc[m][n] = __builtin_amdgcn_mfma_f32_16x16x32_bf16(af[m], bfr[n], acc[m][n], 0, 0, 0);
        __syncthreads();
    }

    // ---- epilogue: D[4*lg + r][l15] per 16x16 fragment ----
    const long coff = (long)zo * sCo + (long)zi * sCi;
    #pragma unroll
    for (int n = 0; n < 4; ++n) {
        const int col = col0 + wn * 64 + n * 16 + l15;
        const float bvv = bias ? bias[col] : 0.0f;
        #pragma unroll
        for (int m = 0; m < 4; ++m) {
            const int rb = row0 + wm * 64 + m * 16 + lg * 4;
            #pragma unroll
            for (int r = 0; r < 4; ++r) {
                float v = acc[m][n][r] + bvv;
                if constexpr (EPI == 0) {
                    float* C = (float*)Cv + coff;
                    long idx = (long)(rb + r) * ldc + col;
                    if constexpr (NT) __builtin_nontemporal_store(v, C + idx);
                    else C[idx] = v;
                } else if constexpr (EPI == 1) {
                    float* C = (float*)Cv + coff;
                    long idx = (long)(rb + r) * ldc + col;
                    C[idx] = C[idx] + v;
                } else {
                    u16* C = (u16*)Cv + coff;
                    if constexpr (EPI == 2)
                        v = 0.5f * v * (1.0f + erff(v * 0.70710678118654752440f));
                    long idx;
                    if constexpr (EPI == 4) {
                        int row = rb + r;
                        idx = (long)(row >> 10) * ((long)HDc * Tc) + (long)col * Tc + (row & 1023);
                    } else {
                        idx = (long)(rb + r) * ldc + col;
                    }
                    C[idx] = f2bf(v);
                }
            }
        }
    }
}

// ---------------- orchestration ----------------
extern "C" void kernel_launch(void* const* d_in, const int* in_sizes, int n_in,
                              void* d_out, int out_size, void* d_ws, size_t ws_size,
                              hipStream_t stream) {
    (void)in_sizes; (void)n_in; (void)out_size; (void)ws_size;
    const int*   x    = (const int*)  d_in[0];
    const float* emb  = (const float*)d_in[1];
    const float* Wq   = (const float*)d_in[2];
    const float* bq   = (const float*)d_in[3];
    const float* Wk   = (const float*)d_in[4];
    const float* bk   = (const float*)d_in[5];
    const float* Wv   = (const float*)d_in[6];
    const float* bv   = (const float*)d_in[7];
    const float* Wo   = (const float*)d_in[8];
    const float* bo   = (const float*)d_in[9];
    const float* ln1g = (const float*)d_in[10];
    const float* ln1b = (const float*)d_in[11];
    const float* ln2g = (const float*)d_in[12];
    const float* ln2b = (const float*)d_in[13];
    const float* W1   = (const float*)d_in[14];
    const float* b1   = (const float*)d_in[15];
    const float* W2   = (const float*)d_in[16];
    const float* b2   = (const float*)d_in[17];
    const float* flng = (const float*)d_in[18];
    const float* flnb = (const float*)d_in[19];
    const float* Wout = (const float*)d_in[20];
    float* out = (float*)d_out;

    // workspace (≈113 MB):
    // h fp32 [BT,D] | S fp32 [8,T,T] | xn bf16 [BT,D] | Q bf16 [BT,4096] |
    // K bf16 [BT,4096] | Vt bf16 [B][4096][T] | P bf16 [8,T,T]
    // aliases: y (attn out bf16) <- K ; mff bf16 <- Q
    float* h  = (float*)d_ws;
    float* Sb = h + (long)BTc * Dc;
    u16* xnb  = (u16*)(Sb + (long)Bc * Hc * Tc * Tc);
    u16* Qb   = xnb + (long)BTc * Dc;
    u16* Kb   = Qb + (long)BTc * HDc;
    u16* Vt   = Kb + (long)BTc * HDc;
    u16* Pb   = Vt + (long)BTc * HDc;
    u16* yb   = Kb;
    u16* mffb = Qb;

    embed_kernel<<<(BTc * Dc) / 256, 256, 0, stream>>>(x, emb, h);

    for (int l = 0; l < Lc; ++l) {
        layernorm_kernel<<<BTc, 256, 0, stream>>>(h, ln1g + l * Dc, ln1b + l * Dc, xnb);

        // fused-head QKV projections: M=2048, N=4096, K=1024, per-head weight slab via HEADB
        dim3 gqkv(HDc / 128, BTc / 128, 1);
        bgemm<false, true, 3, false, false, false><<<gqkv, 256, 0, stream>>>(
            xnb, Wq + (long)l * HDc * Dc, bq + (long)l * HDc, Qb,
            BTc, HDc, Dc, Dc, Dc, HDc, 1, 0, 0, 0, 0, 0, 0, (long)Dc * Dc);
        bgemm<false, true, 3, false, false, false><<<gqkv, 256, 0, stream>>>(
            xnb, Wk + (long)l * HDc * Dc, bk + (long)l * HDc, Kb,
            BTc, HDc, Dc, Dc, Dc, HDc, 1, 0, 0, 0, 0, 0, 0, (long)Dc * Dc);
        bgemm<false, true, 4, false, false, false><<<gqkv, 256, 0, stream>>>(
            xnb, Wv + (long)l * HDc * Dc, bv + (long)l * HDc, Vt,
            BTc, HDc, Dc, Dc, Dc, HDc, 1, 0, 0, 0, 0, 0, 0, (long)Dc * Dc);

        // S = Q @ K^T per z=(h*B+b); causal block skip
        dim3 gs(Tc / 128, Tc / 128, Bc * Hc);
        bgemm<true, false, 0, true, false, false><<<gs, 256, 0, stream>>>(
            Qb, Kb, nullptr, Sb, Tc, Tc, Dc, HDc, HDc, Tc,
            Bc, (long)Dc, (long)Tc * HDc, (long)Dc, (long)Tc * HDc,
            (long)2 * Tc * Tc, (long)Tc * Tc, 0);

        softmax_causal_kernel<<<dim3(Tc, Bc * Hc), 256, 0, stream>>>(Sb, Pb);

        // y = P @ V  (V pre-transposed, K-loop limited to row0+128)
        bgemm<true, false, 3, false, true, false><<<gs, 256, 0, stream>>>(
            Pb, Vt, nullptr, yb, Tc, Dc, Tc, Tc, Tc, HDc,
            Bc, (long)2 * Tc * Tc, (long)Tc * Tc, (long)Dc * Tc, (long)HDc * Tc,
            (long)Dc, (long)Tc * HDc, 0);

        // h += y @ Wo + bo (single K=4096 GEMM)
        bgemm<false, false, 1, false, false, false><<<dim3(Dc / 128, BTc / 128, 1), 256, 0, stream>>>(
            yb, Wo + (long)l * HDc * Dc, bo + (long)l * Dc, h,
            BTc, Dc, HDc, HDc, Dc, Dc, 1, 0, 0, 0, 0, 0, 0, 0);

        // MLP
        layernorm_kernel<<<BTc, 256, 0, stream>>>(h, ln2g + l * Dc, ln2b + l * Dc, xnb);
        bgemm<false, false, 2, false, false, false><<<dim3(DFFc / 128, BTc / 128, 1), 256, 0, stream>>>(
            xnb, W1 + (long)l * Dc * DFFc, b1 + (long)l * DFFc, mffb,
            BTc, DFFc, Dc, Dc, DFFc, DFFc, 1, 0, 0, 0, 0, 0, 0, 0);
        bgemm<false, false, 1, false, false, false><<<dim3(Dc / 128, BTc / 128, 1), 256, 0, stream>>>(
            mffb, W2 + (long)l * DFFc * Dc, b2 + (long)l * Dc, h,
            BTc, Dc, DFFc, DFFc, Dc, Dc, 1, 0, 0, 0, 0, 0, 0, 0);
    }

    layernorm_kernel<<<BTc, 256, 0, stream>>>(h, flng, flnb, xnb);
    // final projection: NT stores keep Wout L3-resident
    bgemm<false, false, 0, false, false, true><<<dim3(Vc / 128, BTc / 128, 1), 256, 0, stream>>>(
        xnb, Wout, nullptr, out, BTc, Vc, Dc, Dc, Vc, Vc, 1, 0, 0, 0, 0, 0, 0, 0);
    log_softmax_kernel<<<BTc, 256, 0, stream>>>(out);
}

// Round 4
// 2721.957 us; speedup vs baseline: 3.8375x; 1.2918x over previous
//
#include <hip/hip_runtime.h>
#include <math.h>

// Problem constants
#define Lc 4
#define Hc 4
#define Bc 2
#define Tc 1024
#define Dc 1024
#define DFFc 4096
#define Vc 32000
#define BTc (Bc * Tc)
#define HDc (Hc * Dc) // 4096

typedef unsigned int u32;
typedef unsigned short u16;
typedef __attribute__((ext_vector_type(8))) short bh8;   // 8 x bf16 (4 VGPR)
typedef __attribute__((ext_vector_type(4))) float f4v;   // MFMA accumulator

constexpr float EPSc = 1e-5f;
constexpr float SCALEc = 0.03125f; // 1/sqrt(1024)

// ---------------- conversion helpers ----------------
__device__ __forceinline__ u16 f2bf(float f) {
    u32 u = __builtin_bit_cast(u32, f);
    u = u + 0x7FFFu + ((u >> 16) & 1u); // RNE
    return (u16)(u >> 16);
}
__device__ __forceinline__ u32 cvt2(float a, float b) {
    return (u32)f2bf(a) | ((u32)f2bf(b) << 16); // lo = a, hi = b
}
typedef const __attribute__((address_space(1))) void* gas1_t;
typedef __attribute__((address_space(3))) void* las3_t;
__device__ __forceinline__ void gload16(const void* g, void* l) {
    // async global->LDS, 16B per lane, LDS dest = wave-uniform base + lane*16
    __builtin_amdgcn_global_load_lds((gas1_t)g, (las3_t)l, 16, 0, 0);
}

// ---------------- reduction helpers (blockDim.x == 256) ----------------
__device__ __forceinline__ float block_reduce_max(float v) {
    #pragma unroll
    for (int o = 32; o > 0; o >>= 1) v = fmaxf(v, __shfl_down(v, o, 64));
    __shared__ float sm_[4];
    __syncthreads();
    if ((threadIdx.x & 63) == 0) sm_[threadIdx.x >> 6] = v;
    __syncthreads();
    return fmaxf(fmaxf(sm_[0], sm_[1]), fmaxf(sm_[2], sm_[3]));
}

__device__ __forceinline__ float block_reduce_sum(float v) {
    #pragma unroll
    for (int o = 32; o > 0; o >>= 1) v += __shfl_down(v, o, 64);
    __shared__ float ss_[4];
    __syncthreads();
    if ((threadIdx.x & 63) == 0) ss_[threadIdx.x >> 6] = v;
    __syncthreads();
    return ss_[0] + ss_[1] + ss_[2] + ss_[3];
}

// ---------------- embed: h = token_emb[x] + pos_embed (fp32) ----------------
__global__ __launch_bounds__(256) void embed_kernel(const int* __restrict__ x,
                                                    const float* __restrict__ emb,
                                                    float* __restrict__ h) {
    long idx = (long)blockIdx.x * 256 + threadIdx.x; // < BT*D
    int d = (int)(idx & (Dc - 1));
    long bt = idx >> 10;
    int t = (int)(bt & (Tc - 1));
    int tok = x[bt];
    float denom = powf(10000.0f, (float)(2 * (d >> 1)) * (1.0f / Dc));
    float ang = (float)t / denom;
    float p = (d & 1) ? cosf(ang) : sinf(ang);
    h[idx] = emb[(long)tok * Dc + d] + p;
}

// ---------------- layernorm over D=1024 -> bf16 output ----------------
__global__ __launch_bounds__(256) void layernorm_kernel(const float* __restrict__ X,
                                                        const float* __restrict__ g,
                                                        const float* __restrict__ b,
                                                        u16* __restrict__ Y) {
    long row = blockIdx.x;
    float4 v = ((const float4*)(X + row * Dc))[threadIdx.x];
    float s  = v.x + v.y + v.z + v.w;
    float sq = v.x * v.x + v.y * v.y + v.z * v.z + v.w * v.w;
    #pragma unroll
    for (int o = 32; o > 0; o >>= 1) {
        s  += __shfl_down(s, o, 64);
        sq += __shfl_down(sq, o, 64);
    }
    __shared__ float ssum[4], ssq[4];
    if ((threadIdx.x & 63) == 0) { ssum[threadIdx.x >> 6] = s; ssq[threadIdx.x >> 6] = sq; }
    __syncthreads();
    s  = ssum[0] + ssum[1] + ssum[2] + ssum[3];
    sq = ssq[0] + ssq[1] + ssq[2] + ssq[3];
    float mu  = s * (1.0f / Dc);
    float var = sq * (1.0f / Dc) - mu * mu;
    float inv = rsqrtf(var + EPSc);
    float4 gv = ((const float4*)g)[threadIdx.x];
    float4 bv = ((const float4*)b)[threadIdx.x];
    float o0 = (v.x - mu) * inv * gv.x + bv.x;
    float o1 = (v.y - mu) * inv * gv.y + bv.y;
    float o2 = (v.z - mu) * inv * gv.z + bv.z;
    float o3 = (v.w - mu) * inv * gv.w + bv.w;
    uint2 o; o.x = cvt2(o0, o1); o.y = cvt2(o2, o3);
    ((uint2*)(Y + row * Dc))[threadIdx.x] = o;
}

// ---------------- causal softmax: fp32 S in, bf16 P out (applies scale) ----------------
__global__ __launch_bounds__(256) void softmax_causal_kernel(const float* __restrict__ S,
                                                             u16* __restrict__ P) {
    int t = blockIdx.x;
    long z = blockIdx.y;
    const float* row = S + (z * Tc + t) * (long)Tc;
    u16* prow = P + (z * Tc + t) * (long)Tc;
    int n = t + 1;
    float m = -INFINITY;
    for (int s = threadIdx.x; s < n; s += 256) m = fmaxf(m, row[s] * SCALEc);
    m = block_reduce_max(m);
    float sum = 0.0f;
    for (int s = threadIdx.x; s < n; s += 256) sum += expf(row[s] * SCALEc - m);
    sum = block_reduce_sum(sum);
    float r = 1.0f / sum;
    for (int s = threadIdx.x; s < Tc; s += 256) {
        float p = (s < n) ? expf(row[s] * SCALEc - m) * r : 0.0f;
        prow[s] = f2bf(p);
    }
}

// ---------------- in-place log_softmax over V=32000, online 2-pass, float4 ----------------
__global__ __launch_bounds__(256) void log_softmax_kernel(float* __restrict__ O) {
    float4* x = (float4*)(O + (long)blockIdx.x * Vc);
    float m = -INFINITY, s = 0.0f;
    for (int i = threadIdx.x; i < Vc / 4; i += 256) {
        float4 v = x[i];
        float mv = fmaxf(fmaxf(v.x, v.y), fmaxf(v.z, v.w));
        if (mv > m) { s *= expf(m - mv); m = mv; }
        s += expf(v.x - m) + expf(v.y - m) + expf(v.z - m) + expf(v.w - m);
    }
    float M = block_reduce_max(m);
    s *= expf(m - M);
    s = block_reduce_sum(s);
    float lse = M + logf(s);
    for (int i = threadIdx.x; i < Vc / 4; i += 256) {
        float4 v = x[i];
        v.x -= lse; v.y -= lse; v.z -= lse; v.w -= lse;
        x[i] = v;
    }
}

// ---------------- transpose+convert: out[n][k] (bf16) = in[k][n] (fp32) ----------------
// in piece: [K][N] fp32, row stride N. out piece: [N][K] bf16. z batches pieces.
// grid: (N/64, K/64, pieces)
__global__ __launch_bounds__(256) void tconv_kernel(
    const float* __restrict__ in, u16* __restrict__ out,
    int K, int N, long sIn, long sOut) {
    in  += (long)blockIdx.z * sIn;
    out += (long)blockIdx.z * sOut;
    const int n0 = blockIdx.x * 64, k0 = blockIdx.y * 64;
    __shared__ float tile[64][65];
    const int t = threadIdx.x;
    const int rc = (t & 15) * 4, rr = t >> 4;
    #pragma unroll
    for (int i = 0; i < 4; ++i) {
        float4 v = *(const float4*)(in + (long)(k0 + rr + 16 * i) * N + (n0 + rc));
        tile[rr + 16 * i][rc + 0] = v.x;
        tile[rr + 16 * i][rc + 1] = v.y;
        tile[rr + 16 * i][rc + 2] = v.z;
        tile[rr + 16 * i][rc + 3] = v.w;
    }
    __syncthreads();
    const int wn = t >> 2, kc = (t & 3) * 16;
    float f[16];
    #pragma unroll
    for (int j = 0; j < 16; ++j) f[j] = tile[kc + j][wn];
    uint4 u0, u1;
    u0.x = cvt2(f[0], f[1]);   u0.y = cvt2(f[2], f[3]);
    u0.z = cvt2(f[4], f[5]);   u0.w = cvt2(f[6], f[7]);
    u1.x = cvt2(f[8], f[9]);   u1.y = cvt2(f[10], f[11]);
    u1.z = cvt2(f[12], f[13]); u1.w = cvt2(f[14], f[15]);
    u16* dp = out + (long)(n0 + wn) * K + (k0 + kc);
    *(uint4*)dp = u0;
    *(uint4*)(dp + 8) = u1;
}

// ---------------- bf16 MFMA GEMM, 128x128 tile, BK=32, 4 waves, all-TRANSB ----------------
// A: bf16 [M][K] row-major (lda); B: bf16 [N][K] row-major (ldb). Both via global_load_lds
// with chunk-XOR swizzle (source-side XOR + read-side XOR, rule #21 both-sides).
// Batch z: off = (z/zdiv)*s?o + (z%zdiv)*s?i (element strides).
// EPI: 0 fp32 store (+NT), 1 fp32 residual add, 2 gelu->bf16, 3 (+bias)->bf16,
//      4 (+bias)->bf16 transposed V layout [b][col][t].
// CAUSAL: skip blocks fully above diagonal. KLIM: Kend = min(K, row0+128).
// SWAPG: row0 from blockIdx.x (fast) so blocks sharing a B col-slab are adjacent.
template <int EPI, bool CAUSAL, bool KLIM, bool NT, bool SWAPG>
__global__ __launch_bounds__(256) void bgemm(
    const u16* __restrict__ A, const u16* __restrict__ B,
    const float* __restrict__ bias, void* __restrict__ Cv,
    int K, int lda, int ldb, int ldc,
    int zdiv, long sAo, long sAi, long sBo, long sBi, long sCo, long sCi) {
    const int row0 = (SWAPG ? blockIdx.x : blockIdx.y) * 128;
    const int col0 = (SWAPG ? blockIdx.y : blockIdx.x) * 128;
    if (CAUSAL && col0 > row0 + 127) return;

    const int z = blockIdx.z;
    const int zo = z / zdiv, zi = z - zo * zdiv;

    __shared__ __align__(16) u16 As[128 * 32];
    __shared__ __align__(16) u16 Bs[128 * 32];

    const int tid = threadIdx.x;
    const int wave = tid >> 6, lane = tid & 63;
    const int wm = wave >> 1, wn = wave & 1;
    const int l15 = lane & 15, lg = lane >> 4;
    const int lrow = lane >> 2, lch = lane & 3;
    const int gch = (lch ^ (lrow & 3)) * 8; // source-side chunk XOR (k-offset in elems)

    // staging: wave w stages rows w*32..w*32+31 of each tile (2 gloads per operand)
    const u16* Ag0 = A + (long)zo * sAo + (long)zi * sAi
                   + (long)(row0 + wave * 32 + lrow) * lda + gch;
    const u16* Ag1 = Ag0 + (long)16 * lda;
    const u16* Bg0 = B + (long)zo * sBo + (long)zi * sBi
                   + (long)(col0 + wave * 32 + lrow) * ldb + gch;
    const u16* Bg1 = Bg0 + (long)16 * ldb;
    u16* Al0 = As + wave * 1024; u16* Al1 = Al0 + 512;
    u16* Bl0 = Bs + wave * 1024; u16* Bl1 = Bl0 + 512;

    // fragment LDS offsets with read-side XOR (row&3 == l15&3 for all sub-tiles)
    const int rsw = (lg ^ (l15 & 3)) * 8;
    int aoff[4], boff[4];
    #pragma unroll
    for (int m = 0; m < 4; ++m) aoff[m] = (wm * 64 + m * 16 + l15) * 32 + rsw;
    #pragma unroll
    for (int n = 0; n < 4; ++n) boff[n] = (wn * 64 + n * 16 + l15) * 32 + rsw;

    f4v acc[4][4];
    const f4v fz = {0.f, 0.f, 0.f, 0.f};
    #pragma unroll
    for (int m = 0; m < 4; ++m)
        #pragma unroll
        for (int n = 0; n < 4; ++n) acc[m][n] = fz;

    const int Kend = KLIM ? min(K, row0 + 128) : K;

    for (int k0 = 0; k0 < Kend; k0 += 32) {
        gload16(Ag0, Al0);
        gload16(Ag1, Al1);
        gload16(Bg0, Bl0);
        gload16(Bg1, Bl1);
        Ag0 += 32; Ag1 += 32; Bg0 += 32; Bg1 += 32;
        __syncthreads();
        bh8 af[4], bfr[4];
        #pragma unroll
        for (int m = 0; m < 4; ++m) af[m] = *(const bh8*)(As + aoff[m]);
        #pragma unroll
        for (int n = 0; n < 4; ++n) bfr[n] = *(const bh8*)(Bs + boff[n]);
        #pragma unroll
        for (int m = 0; m < 4; ++m)
            #pragma unroll
            for (int n = 0; n < 4; ++n)
                acc[m][n] = __builtin_amdgcn_mfma_f32_16x16x32_bf16(af[m], bfr[n], acc[m][n], 0, 0, 0);
        __syncthreads();
    }

    // ---- epilogue: D[4*lg + r][l15] per 16x16 fragment ----
    const long coff = (long)zo * sCo + (long)zi * sCi;
    #pragma unroll
    for (int n = 0; n < 4; ++n) {
        const int col = col0 + wn * 64 + n * 16 + l15;
        const float bvv = bias ? bias[col] : 0.0f;
        #pragma unroll
        for (int m = 0; m < 4; ++m) {
            const int rb = row0 + wm * 64 + m * 16 + lg * 4;
            #pragma unroll
            for (int r = 0; r < 4; ++r) {
                float v = acc[m][n][r] + bvv;
                if constexpr (EPI == 0) {
                    float* C = (float*)Cv + coff;
                    long idx = (long)(rb + r) * ldc + col;
                    if constexpr (NT) __builtin_nontemporal_store(v, C + idx);
                    else C[idx] = v;
                } else if constexpr (EPI == 1) {
                    float* C = (float*)Cv + coff;
                    long idx = (long)(rb + r) * ldc + col;
                    C[idx] = C[idx] + v;
                } else {
                    u16* C = (u16*)Cv + coff;
                    if constexpr (EPI == 2)
                        v = 0.5f * v * (1.0f + erff(v * 0.70710678118654752440f));
                    long idx;
                    if constexpr (EPI == 4) {
                        int row = rb + r;
                        idx = (long)(row >> 10) * ((long)HDc * Tc) + (long)col * Tc + (row & 1023);
                    } else {
                        idx = (long)(rb + r) * ldc + col;
                    }
                    C[idx] = f2bf(v);
                }
            }
        }
    }
}

// ---------------- orchestration ----------------
extern "C" void kernel_launch(void* const* d_in, const int* in_sizes, int n_in,
                              void* d_out, int out_size, void* d_ws, size_t ws_size,
                              hipStream_t stream) {
    (void)in_sizes; (void)n_in; (void)out_size; (void)ws_size;
    const int*   x    = (const int*)  d_in[0];
    const float* emb  = (const float*)d_in[1];
    const float* Wq   = (const float*)d_in[2];
    const float* bq   = (const float*)d_in[3];
    const float* Wk   = (const float*)d_in[4];
    const float* bk   = (const float*)d_in[5];
    const float* Wv   = (const float*)d_in[6];
    const float* bv   = (const float*)d_in[7];
    const float* Wo   = (const float*)d_in[8];
    const float* bo   = (const float*)d_in[9];
    const float* ln1g = (const float*)d_in[10];
    const float* ln1b = (const float*)d_in[11];
    const float* ln2g = (const float*)d_in[12];
    const float* ln2b = (const float*)d_in[13];
    const float* W1   = (const float*)d_in[14];
    const float* b1   = (const float*)d_in[15];
    const float* W2   = (const float*)d_in[16];
    const float* b2   = (const float*)d_in[17];
    const float* flng = (const float*)d_in[18];
    const float* flnb = (const float*)d_in[19];
    const float* Wout = (const float*)d_in[20];
    float* out = (float*)d_out;

    // workspace (~116 MB):
    // h fp32 [BT,D] | S fp32 [8,T,T] | xn bf16 [BT,D] | Q bf16 [BT,4096] |
    // K bf16 [BT,4096] | Vt bf16 [B][4096][T] | P bf16 [8,T,T] | WT bf16 [4096][1024]
    // aliases: y <- K ; mff <- Q ; WoutT bf16 [32000][1024] <- Q..P (dead at final)
    float* h  = (float*)d_ws;
    float* Sb = h + (long)BTc * Dc;
    u16* xnb  = (u16*)(Sb + (long)Bc * Hc * Tc * Tc);
    u16* Qb   = xnb + (long)BTc * Dc;
    u16* Kb   = Qb + (long)BTc * HDc;
    u16* Vt   = Kb + (long)BTc * HDc;
    u16* Pb   = Vt + (long)BTc * HDc;
    u16* WT   = Pb + (long)Bc * Hc * Tc * Tc;
    u16* yb   = Kb;
    u16* mffb = Qb;
    u16* WoutT = Qb; // 65.5 MB, fits in Q+K+Vt+P (67.1 MB), all dead at final GEMM

    embed_kernel<<<(BTc * Dc) / 256, 256, 0, stream>>>(x, emb, h);

    for (int l = 0; l < Lc; ++l) {
        layernorm_kernel<<<BTc, 256, 0, stream>>>(h, ln1g + l * Dc, ln1b + l * Dc, xnb);

        // QKV projections: transpose W -> [4096][1024] bf16, then TN GEMM
        tconv_kernel<<<dim3(16, 16, 4), 256, 0, stream>>>(
            Wq + (long)l * HDc * Dc, WT, Dc, Dc, (long)Dc * Dc, (long)Dc * Dc);
        bgemm<3, false, false, false, false><<<dim3(HDc / 128, BTc / 128, 1), 256, 0, stream>>>(
            xnb, WT, bq + (long)l * HDc, Qb, Dc, Dc, Dc, HDc, 1, 0, 0, 0, 0, 0, 0);
        tconv_kernel<<<dim3(16, 16, 4), 256, 0, stream>>>(
            Wk + (long)l * HDc * Dc, WT, Dc, Dc, (long)Dc * Dc, (long)Dc * Dc);
        bgemm<3, false, false, false, false><<<dim3(HDc / 128, BTc / 128, 1), 256, 0, stream>>>(
            xnb, WT, bk + (long)l * HDc, Kb, Dc, Dc, Dc, HDc, 1, 0, 0, 0, 0, 0, 0);
        tconv_kernel<<<dim3(16, 16, 4), 256, 0, stream>>>(
            Wv + (long)l * HDc * Dc, WT, Dc, Dc, (long)Dc * Dc, (long)Dc * Dc);
        bgemm<4, false, false, false, false><<<dim3(HDc / 128, BTc / 128, 1), 256, 0, stream>>>(
            xnb, WT, bv + (long)l * HDc, Vt, Dc, Dc, Dc, HDc, 1, 0, 0, 0, 0, 0, 0);

        // S = Q @ K^T per z=(h*B+b); causal block skip
        dim3 gs(Tc / 128, Tc / 128, Bc * Hc);
        bgemm<0, true, false, false, false><<<gs, 256, 0, stream>>>(
            Qb, Kb, nullptr, Sb, Dc, HDc, HDc, Tc,
            Bc, (long)Dc, (long)Tc * HDc, (long)Dc, (long)Tc * HDc,
            (long)2 * Tc * Tc, (long)Tc * Tc);

        softmax_causal_kernel<<<dim3(Tc, Bc * Hc), 256, 0, stream>>>(Sb, Pb);

        // y = P @ V  (V pre-transposed, K-loop limited to row0+128)
        bgemm<3, false, true, false, false><<<gs, 256, 0, stream>>>(
            Pb, Vt, nullptr, yb, Tc, Tc, Tc, HDc,
            Bc, (long)2 * Tc * Tc, (long)Tc * Tc, (long)Dc * Tc, (long)HDc * Tc,
            (long)Dc, (long)Tc * HDc);

        // h += y @ Wo + bo
        tconv_kernel<<<dim3(16, 64, 1), 256, 0, stream>>>(
            Wo + (long)l * HDc * Dc, WT, HDc, Dc, 0, 0);
        bgemm<1, false, false, false, false><<<dim3(Dc / 128, BTc / 128, 1), 256, 0, stream>>>(
            yb, WT, bo + (long)l * Dc, h, HDc, HDc, HDc, Dc, 1, 0, 0, 0, 0, 0, 0);

        // MLP
        layernorm_kernel<<<BTc, 256, 0, stream>>>(h, ln2g + l * Dc, ln2b + l * Dc, xnb);
        tconv_kernel<<<dim3(64, 16, 1), 256, 0, stream>>>(
            W1 + (long)l * Dc * DFFc, WT, Dc, DFFc, 0, 0);
        bgemm<2, false, false, false, false><<<dim3(DFFc / 128, BTc / 128, 1), 256, 0, stream>>>(
            xnb, WT, b1 + (long)l * DFFc, mffb, Dc, Dc, Dc, DFFc, 1, 0, 0, 0, 0, 0, 0);
        tconv_kernel<<<dim3(16, 64, 1), 256, 0, stream>>>(
            W2 + (long)l * DFFc * Dc, WT, DFFc, Dc, 0, 0);
        bgemm<1, false, false, false, false><<<dim3(Dc / 128, BTc / 128, 1), 256, 0, stream>>>(
            mffb, WT, b2 + (long)l * Dc, h, DFFc, DFFc, DFFc, Dc, 1, 0, 0, 0, 0, 0, 0);
    }

    layernorm_kernel<<<BTc, 256, 0, stream>>>(h, flng, flnb, xnb);
    // final projection: transpose Wout -> [32000][1024] bf16 (into dead Q..P region),
    // SWAPG grid so row-blocks sharing a col-slab are adjacent; NT stores for output
    tconv_kernel<<<dim3(500, 16, 1), 256, 0, stream>>>(Wout, WoutT, Dc, Vc, 0, 0);
    bgemm<0, false, false, true, true><<<dim3(BTc / 128, Vc / 128, 1), 256, 0, stream>>>(
        xnb, WoutT, nullptr, out, Dc, Dc, Dc, Vc, 1, 0, 0, 0, 0, 0, 0);
    log_softmax_kernel<<<BTc, 256, 0, stream>>>(out);
}